// Round 5
// baseline (246.668 us; speedup 1.0000x reference)
//
#include <hip/hip_runtime.h>
#include <cstdint>
#include <cstddef>

typedef __bf16 bf16x8 __attribute__((ext_vector_type(8)));
typedef __bf16 bf16x2v __attribute__((ext_vector_type(2)));
typedef unsigned short u16;
typedef u16 u16x8v __attribute__((ext_vector_type(8)));
typedef float  f32x4  __attribute__((ext_vector_type(4)));
typedef unsigned int u32;

#define MFMA16(a, b, c) __builtin_amdgcn_mfma_f32_16x16x32_bf16((a), (b), (c), 0, 0, 0)
#define ASYNC16(g, l)                                                              \
  __builtin_amdgcn_global_load_lds(                                                \
      (const __attribute__((address_space(1))) unsigned int*)(g),                  \
      (__attribute__((address_space(3))) unsigned int*)(l), 16, 0, 0)

__device__ __forceinline__ u16 f2bf(float f) {
  unsigned u = __builtin_bit_cast(unsigned, f);
  u += 0x7fffu + ((u >> 16) & 1u);
  return (u16)(u >> 16);
}

// packed fp32x2 -> bf16x2 (RNE) via hardware cvt
__device__ __forceinline__ u32 cvt2(float a, float b) {
  bf16x2v t;
  t[0] = (__bf16)a;
  t[1] = (__bf16)b;
  return __builtin_bit_cast(u32, t);
}

#define SEQ 2048
#define CH  1024
#define NH  16
#define HD  64
// log2(e) / sqrt(64) folded into stored Q so softmax uses exp2
#define QSCALE 0.18033688011112042f

// ------------- fused prep: cast x + transpose-cast qkv_w + proj_w -------------
// (round-2 version, measured-best)
__global__ void __launch_bounds__(256) prep_kernel(const float* __restrict__ x,
                                                   const float* __restrict__ qkv_w,
                                                   const float* __restrict__ proj_w,
                                                   u16* __restrict__ xb,
                                                   u16* __restrict__ wqkvt,
                                                   u16* __restrict__ wprojt) {
  __shared__ u16 t[64][68];
  int bx = blockIdx.x;
  int tx = threadIdx.x;
  if (bx < 4096) {
    int i = bx * 256 + tx;
    float4 v = ((const float4*)x)[i];
    ushort4 o;
    o.x = f2bf(v.x); o.y = f2bf(v.y); o.z = f2bf(v.z); o.w = f2bf(v.w);
    ((ushort4*)xb)[i] = o;
    return;
  }
  const float* in; u16* out; int R, C, c0, r0;
  if (bx < 4096 + 768) {
    int i = bx - 4096;
    in = qkv_w; out = wqkvt; R = 1024; C = 3072;
    c0 = (i % 48) * 64; r0 = (i / 48) * 64;
  } else {
    int i = bx - 4864;
    in = proj_w; out = wprojt; R = 1024; C = 1024;
    c0 = (i % 16) * 64; r0 = (i / 16) * 64;
  }
  int rr = tx >> 6, cc = tx & 63;
#pragma unroll
  for (int i = 0; i < 16; ++i) {
    int r = i * 4 + rr;
    t[r][cc] = f2bf(in[(size_t)(r0 + r) * C + c0 + cc]);
  }
  __syncthreads();
#pragma unroll
  for (int i = 0; i < 16; ++i) {
    int r = i * 4 + rr;
    out[(size_t)(c0 + r) * R + r0 + cc] = t[cc][r];
  }
}

// ------------- GEMM v4 (round-2 version, measured-best): BK=64, XOR-swizzled LDS,
//               double-buffered staging, two barriers/iter, coalesced epilogue ----
template <int MT>
__global__ void __launch_bounds__(256) gemm_kernel(const u16* __restrict__ A,
                                                   const u16* __restrict__ Bt,
                                                   const float* __restrict__ bias,
                                                   u16* __restrict__ qk,
                                                   u16* __restrict__ vtout,
                                                   float* __restrict__ outf,
                                                   int K, int mode) {
  constexpr int R = MT * 32;
  __shared__ alignas(16) u16 smem[2 * R * 64 + 2 * 128 * 64];
  auto As = (u16(*)[R * 64])smem;
  auto Bs = (u16(*)[128 * 64])(smem + 2 * R * 64);
  int tid = threadIdx.x;
  int lane = tid & 63, wave = tid >> 6;
  int wm = wave >> 1, wn = wave & 1;
  int qr = lane & 15, quad = lane >> 4;
  size_t rowA = (size_t)blockIdx.y * R;
  size_t rowB = (size_t)blockIdx.x * 128;

  int klr = lane >> 3;
  int kcs = (lane & 7) ^ klr;

  f32x4 acc[MT][4];
#pragma unroll
  for (int mt = 0; mt < MT; ++mt)
#pragma unroll
    for (int nt = 0; nt < 4; ++nt) acc[mt][nt] = (f32x4){0.f, 0.f, 0.f, 0.f};

  auto stage = [&](int buf, int k0) {
#pragma unroll
    for (int i = 0; i < R / 32; ++i) {
      int ar = wave * (R / 4) + i * 8;
      ASYNC16(A + (rowA + ar + klr) * K + k0 + kcs * 8, &As[buf][ar * 64 + lane * 8]);
    }
#pragma unroll
    for (int i = 0; i < 4; ++i) {
      int br = wave * 32 + i * 8;
      ASYNC16(Bt + (rowB + br + klr) * K + k0 + kcs * 8, &Bs[buf][br * 64 + lane * 8]);
    }
  };

  stage(0, 0);
  int iters = K >> 6;
  for (int t = 0; t < iters; ++t) {
    int cur = t & 1;
    __syncthreads();  // drains DMA into buf[cur]; all waves done reading buf[cur^1]
    if (t + 1 < iters) stage(cur ^ 1, (t + 1) * 64);
#pragma unroll
    for (int ks = 0; ks < 2; ++ks) {
      bf16x8 af[MT], bfr[4];
#pragma unroll
      for (int mt = 0; mt < MT; ++mt) {
        int row = wm * (MT * 16) + mt * 16 + qr;
        af[mt] = *(const bf16x8*)&As[cur][row * 64 + (((ks * 4 + quad) ^ (qr & 7)) << 3)];
      }
#pragma unroll
      for (int nt = 0; nt < 4; ++nt) {
        int row = wn * 64 + nt * 16 + qr;
        bfr[nt] = *(const bf16x8*)&Bs[cur][row * 64 + (((ks * 4 + quad) ^ (qr & 7)) << 3)];
      }
#pragma unroll
      for (int mt = 0; mt < MT; ++mt)
#pragma unroll
        for (int nt = 0; nt < 4; ++nt)
          acc[mt][nt] = MFMA16(af[mt], bfr[nt], acc[mt][nt]);
    }
    __syncthreads();  // reads of buf[cur] done before next iter's stage overwrites
  }

  __syncthreads();  // compute done; smem reusable for epilogue staging

  if (mode == 1) {
    // fp32 tile [R][128], padded stride 132 floats (528B, 16B-aligned rows)
    float* epf = (float*)smem;
#pragma unroll
    for (int nt = 0; nt < 4; ++nt) {
      int cl = wn * 64 + nt * 16 + qr;
      float bv = bias[rowB + cl];
#pragma unroll
      for (int mt = 0; mt < MT; ++mt) {
        int rl = wm * (MT * 16) + mt * 16 + quad * 4;
#pragma unroll
        for (int r = 0; r < 4; ++r)
          epf[(rl + r) * 132 + cl] = acc[mt][nt][r] + bv;
      }
    }
    __syncthreads();
    int rr = wave * 2 + (lane >> 5);
    int cc = (lane & 31) * 4;
#pragma unroll
    for (int p = 0; p < R / 8; ++p) {
      int row = p * 8 + rr;
      float4 v = *(const float4*)&epf[row * 132 + cc];
      *(float4*)&outf[(rowA + row) * 1024 + rowB + cc] = v;
    }
  } else if ((int)rowB < 2048) {
    // Q (scaled) / K -> packed QK buffer (stride 2048), coalesced 16B stores
    float sc = ((int)rowB < 1024) ? QSCALE : 1.0f;  // whole 128-col tile is Q or K
    u16* ep = smem;  // [R][128] u16, padded stride 136 (272B, 16B-aligned rows)
#pragma unroll
    for (int nt = 0; nt < 4; ++nt) {
      int cl = wn * 64 + nt * 16 + qr;
      float bv = bias[rowB + cl];
#pragma unroll
      for (int mt = 0; mt < MT; ++mt) {
        int rl = wm * (MT * 16) + mt * 16 + quad * 4;
#pragma unroll
        for (int r = 0; r < 4; ++r)
          ep[(rl + r) * 136 + cl] = f2bf((acc[mt][nt][r] + bv) * sc);
      }
    }
    __syncthreads();
    int rr = wave * 4 + (lane >> 4);
    int cc = (lane & 15) * 8;
#pragma unroll
    for (int p = 0; p < R / 16; ++p) {
      int row = p * 16 + rr;
      u16x8v v = *(const u16x8v*)&ep[row * 136 + cc];
      *(u16x8v*)&qk[(rowA + row) * 2048 + rowB + cc] = v;
    }
  } else {
    // V -> vt[bh][d][n]: stage transposed tile [d][n] in LDS, then write
    // coalesced 256B rows along n.
    u16* ep = smem;  // [128 d][R n] u16, padded stride 136
#pragma unroll
    for (int nt = 0; nt < 4; ++nt) {
      int cl = wn * 64 + nt * 16 + qr;  // d_local 0..127
      float bv = bias[rowB + cl];
#pragma unroll
      for (int mt = 0; mt < MT; ++mt) {
        int rl = wm * (MT * 16) + mt * 16 + quad * 4;  // n_local, multiple of 4
        ushort4 pv;
        pv.x = f2bf(acc[mt][nt][0] + bv);
        pv.y = f2bf(acc[mt][nt][1] + bv);
        pv.z = f2bf(acc[mt][nt][2] + bv);
        pv.w = f2bf(acc[mt][nt][3] + bv);
        *(ushort4*)&ep[cl * 136 + rl] = pv;
      }
    }
    __syncthreads();
    int batch = (int)(rowA >> 11);
    int n_base = (int)(rowA & 2047);
    int rr = wave * 4 + (lane >> 4);
    int cc = (lane & 15) * 8;
#pragma unroll
    for (int p = 0; p < 8; ++p) {
      int d = p * 16 + rr;                      // 0..127 (2 heads x 64)
      int cglob = (int)rowB - 2048 + d;
      int bh_ = batch * 16 + (cglob >> 6);
      u16x8v v = *(const u16x8v*)&ep[d * 136 + cc];
      *(u16x8v*)&vtout[(size_t)bh_ * 131072 + (size_t)(cglob & 63) * 2048 + n_base + cc] = v;
    }
  }
}

// ------------- flash attention v8: ZERO-barrier streaming, no K/V LDS staging ----
// Rationale (m169 / Common-mistake #7): per-head K,V = 256KB each -> fully L2/L3
// resident (FETCH_SIZE 12MB confirms), and the 4 waves of a block read the SAME
// 16KB K/V tile per step -> L1-shared. LDS staging + its __syncthreads/vmcnt(0)
// drain every 128 keys was pure overhead (the documented ~20% barrier-drain
// stall) and pinned occupancy at 2 blocks/CU (80KB LDS).
// Now: K and V fragments are read directly from global (16B contiguous per lane;
// vt is pre-transposed by gemm1's epilogue). Only the wave-private P round-trip
// (pbuf, 16KB, lgkm-only) stays in LDS. The K-loop has NO barriers and NO DMA.
// vf loads are issued at the top of each 64-key step so their L2 latency hides
// under the QK-MFMA + exp2 phase.
__global__ void __launch_bounds__(256) attn_kernel(const u16* __restrict__ qkbuf,
                                                   const u16* __restrict__ vt,
                                                   u16* __restrict__ out) {
  __shared__ alignas(16) u16 pbuf[4][32 * 64];
  int bh = blockIdx.x;
  int b = bh >> 4, h = bh & 15;
  int m0 = blockIdx.y * 128;
  int tid = threadIdx.x;
  int lane = tid & 63, wave = tid >> 6;
  int qr = lane & 15, quad = lane >> 4;

  const u16* kbase = qkbuf + (size_t)(b * SEQ) * 2048 + 1024 + h * 64;  // K rows, stride 2048
  const u16* vtbase = vt + (size_t)bh * 64 * SEQ;                       // Vt rows, stride 2048
  u16* pw = &pbuf[wave][0];

  // ---- Q fragments (32 rows per wave) ----
  const u16* qbase = qkbuf + (size_t)(b * SEQ + m0 + wave * 32) * 2048 + h * 64;
  bf16x8 qf[2][2];
#pragma unroll
  for (int mt = 0; mt < 2; ++mt)
#pragma unroll
    for (int ks = 0; ks < 2; ++ks)
      qf[mt][ks] = *(const bf16x8*)&qbase[(size_t)(mt * 16 + qr) * 2048 + ks * 32 + quad * 8];

  const bf16x8 vone = __builtin_bit_cast(bf16x8, (u16x8v)((u16)0x3F80));

  f32x4 o[2][4], l5[2];
#pragma unroll
  for (int mt = 0; mt < 2; ++mt) {
    l5[mt] = (f32x4){0.f, 0.f, 0.f, 0.f};
#pragma unroll
    for (int dt = 0; dt < 4; ++dt) o[mt][dt] = (f32x4){0.f, 0.f, 0.f, 0.f};
  }

  for (int t = 0; t < 32; ++t) {  // 64 keys per step
    const u16* kt = kbase + (size_t)(t * 64) * 2048;
    const int n0 = t * 64;

    // issue all K and V fragment loads up-front (independent); V's latency
    // hides under the QK-MFMA + exp2 phase below.
    bf16x8 kf[4][2];
#pragma unroll
    for (int nt = 0; nt < 4; ++nt)
#pragma unroll
      for (int ks = 0; ks < 2; ++ks)
        kf[nt][ks] = *(const bf16x8*)&kt[(size_t)(nt * 16 + qr) * 2048 + ks * 32 + quad * 8];

    bf16x8 vf[4][2];
#pragma unroll
    for (int dt = 0; dt < 4; ++dt)
#pragma unroll
      for (int ks = 0; ks < 2; ++ks)
        vf[dt][ks] =
            *(const bf16x8*)&vtbase[(size_t)(dt * 16 + qr) * 2048 + n0 + ks * 32 + quad * 8];

#pragma unroll
    for (int mt = 0; mt < 2; ++mt)
#pragma unroll
      for (int nt = 0; nt < 4; ++nt) {
        f32x4 z = (f32x4){0.f, 0.f, 0.f, 0.f};
        z = MFMA16(kf[nt][0], qf[mt][0], z);
        z = MFMA16(kf[nt][1], qf[mt][1], z);
        float p0 = __builtin_amdgcn_exp2f(z[0]);
        float p1 = __builtin_amdgcn_exp2f(z[1]);
        float p2 = __builtin_amdgcn_exp2f(z[2]);
        float p3 = __builtin_amdgcn_exp2f(z[3]);
        uint2 pk;
        pk.x = cvt2(p0, p1);
        pk.y = cvt2(p2, p3);
        int nb = nt * 16 + quad * 4;
        int addr = (mt * 16 + qr) * 64 + ((((nb >> 3) ^ (qr & 7)) << 3) | (nb & 7));
        *(uint2*)&pw[addr] = pk;
      }

    bf16x8 pf[2][2];
#pragma unroll
    for (int mt = 0; mt < 2; ++mt)
#pragma unroll
      for (int ks = 0; ks < 2; ++ks)
        pf[mt][ks] =
            *(const bf16x8*)&pw[(mt * 16 + qr) * 64 + (((ks * 4 + quad) ^ (qr & 7)) << 3)];

#pragma unroll
    for (int mt = 0; mt < 2; ++mt) {
#pragma unroll
      for (int dt = 0; dt < 4; ++dt) {
        o[mt][dt] = MFMA16(pf[mt][0], vf[dt][0], o[mt][dt]);
        o[mt][dt] = MFMA16(pf[mt][1], vf[dt][1], o[mt][dt]);
      }
      l5[mt] = MFMA16(pf[mt][0], vone, l5[mt]);
      l5[mt] = MFMA16(pf[mt][1], vone, l5[mt]);
    }
  }

  u16* obase = out + (size_t)(b * SEQ + m0 + wave * 32) * CH + h * 64;
#pragma unroll
  for (int mt = 0; mt < 2; ++mt)
#pragma unroll
    for (int r = 0; r < 4; ++r) {
      float inv = 1.0f / l5[mt][r];
#pragma unroll
      for (int dt = 0; dt < 4; ++dt)
        obase[(size_t)(mt * 16 + quad * 4 + r) * CH + dt * 16 + qr] = f2bf(o[mt][dt][r] * inv);
    }
}

extern "C" void kernel_launch(void* const* d_in, const int* in_sizes, int n_in,
                              void* d_out, int out_size, void* d_ws, size_t ws_size,
                              hipStream_t stream) {
  const float* x      = (const float*)d_in[0];
  const float* qkv_w  = (const float*)d_in[1];
  const float* qkv_b  = (const float*)d_in[2];
  const float* proj_w = (const float*)d_in[3];
  const float* proj_b = (const float*)d_in[4];
  float* out = (float*)d_out;

  char* w = (char*)d_ws;
  // ws layout (42 MB):
  //   qkqk  : 4096x2048 bf16 (Q scaled | K, stride 2048) = 16777216 B
  //   xb    : 4096x1024 bf16 = 8388608 B (reused as attn_bf after gemm1)
  //   wprojt: 1024x1024 bf16 = 2097152 B
  //   wqkvt : 3072x1024 bf16 = 6291456 B
  //   vt    : (B*H)x64x2048 bf16 = 8388608 B (written directly by gemm1 epilogue)
  u16* qkqk   = (u16*)w;
  u16* xb     = (u16*)(w + 16777216);
  u16* wprojt = (u16*)(w + 25165824);
  u16* wqkvt  = (u16*)(w + 27262976);
  u16* vt     = (u16*)(w + 33554432);
  u16* attn_bf = xb;

  prep_kernel<<<5120, 256, 0, stream>>>(x, qkv_w, proj_w, xb, wqkvt, wprojt);
  // qkv = x @ qkv_w + b; Q scaled; QK -> qkqk (stride 2048), V -> vt (transposed)
  gemm_kernel<4><<<dim3(24, 32), 256, 0, stream>>>(xb, wqkvt, qkv_b, qkqk, vt, nullptr, 1024, 0);
  attn_kernel<<<dim3(32, 16), 256, 0, stream>>>(qkqk, vt, attn_bf);
  // out = attn @ proj_w + b (fp32)
  gemm_kernel<2><<<dim3(8, 64), 256, 0, stream>>>(attn_bf, wprojt, proj_b, nullptr, nullptr, out, 1024, 1);
}

// Round 6
// 200.337 us; speedup vs baseline: 1.2313x; 1.2313x over previous
//
#include <hip/hip_runtime.h>
#include <cstdint>
#include <cstddef>

typedef __bf16 bf16x8 __attribute__((ext_vector_type(8)));
typedef __bf16 bf16x2v __attribute__((ext_vector_type(2)));
typedef unsigned short u16;
typedef u16 u16x8v __attribute__((ext_vector_type(8)));
typedef float  f32x4  __attribute__((ext_vector_type(4)));
typedef unsigned int u32;

#define MFMA16(a, b, c) __builtin_amdgcn_mfma_f32_16x16x32_bf16((a), (b), (c), 0, 0, 0)
#define ASYNC16(g, l)                                                              \
  __builtin_amdgcn_global_load_lds(                                                \
      (const __attribute__((address_space(1))) unsigned int*)(g),                  \
      (__attribute__((address_space(3))) unsigned int*)(l), 16, 0, 0)

__device__ __forceinline__ u16 f2bf(float f) {
  unsigned u = __builtin_bit_cast(unsigned, f);
  u += 0x7fffu + ((u >> 16) & 1u);
  return (u16)(u >> 16);
}

// packed fp32x2 -> bf16x2 (RNE) via hardware cvt
__device__ __forceinline__ u32 cvt2(float a, float b) {
  bf16x2v t;
  t[0] = (__bf16)a;
  t[1] = (__bf16)b;
  return __builtin_bit_cast(u32, t);
}

#define SEQ 2048
#define CH  1024
#define NH  16
#define HD  64
// log2(e) / sqrt(64) folded into stored Q so softmax uses exp2
#define QSCALE 0.18033688011112042f

// ------------- fused prep: cast x + transpose-cast qkv_w + proj_w -------------
// (round-2 version, measured-best)
__global__ void __launch_bounds__(256) prep_kernel(const float* __restrict__ x,
                                                   const float* __restrict__ qkv_w,
                                                   const float* __restrict__ proj_w,
                                                   u16* __restrict__ xb,
                                                   u16* __restrict__ wqkvt,
                                                   u16* __restrict__ wprojt) {
  __shared__ u16 t[64][68];
  int bx = blockIdx.x;
  int tx = threadIdx.x;
  if (bx < 4096) {
    int i = bx * 256 + tx;
    float4 v = ((const float4*)x)[i];
    ushort4 o;
    o.x = f2bf(v.x); o.y = f2bf(v.y); o.z = f2bf(v.z); o.w = f2bf(v.w);
    ((ushort4*)xb)[i] = o;
    return;
  }
  const float* in; u16* out; int R, C, c0, r0;
  if (bx < 4096 + 768) {
    int i = bx - 4096;
    in = qkv_w; out = wqkvt; R = 1024; C = 3072;
    c0 = (i % 48) * 64; r0 = (i / 48) * 64;
  } else {
    int i = bx - 4864;
    in = proj_w; out = wprojt; R = 1024; C = 1024;
    c0 = (i % 16) * 64; r0 = (i / 16) * 64;
  }
  int rr = tx >> 6, cc = tx & 63;
#pragma unroll
  for (int i = 0; i < 16; ++i) {
    int r = i * 4 + rr;
    t[r][cc] = f2bf(in[(size_t)(r0 + r) * C + c0 + cc]);
  }
  __syncthreads();
#pragma unroll
  for (int i = 0; i < 16; ++i) {
    int r = i * 4 + rr;
    out[(size_t)(c0 + r) * R + r0 + cc] = t[cc][r];
  }
}

// ------------- GEMM v4 (round-2 version, measured-best): BK=64, XOR-swizzled LDS,
//               double-buffered staging, two barriers/iter, coalesced epilogue ----
template <int MT>
__global__ void __launch_bounds__(256) gemm_kernel(const u16* __restrict__ A,
                                                   const u16* __restrict__ Bt,
                                                   const float* __restrict__ bias,
                                                   u16* __restrict__ qk,
                                                   u16* __restrict__ vtout,
                                                   float* __restrict__ outf,
                                                   int K, int mode) {
  constexpr int R = MT * 32;
  __shared__ alignas(16) u16 smem[2 * R * 64 + 2 * 128 * 64];
  auto As = (u16(*)[R * 64])smem;
  auto Bs = (u16(*)[128 * 64])(smem + 2 * R * 64);
  int tid = threadIdx.x;
  int lane = tid & 63, wave = tid >> 6;
  int wm = wave >> 1, wn = wave & 1;
  int qr = lane & 15, quad = lane >> 4;
  size_t rowA = (size_t)blockIdx.y * R;
  size_t rowB = (size_t)blockIdx.x * 128;

  int klr = lane >> 3;
  int kcs = (lane & 7) ^ klr;

  f32x4 acc[MT][4];
#pragma unroll
  for (int mt = 0; mt < MT; ++mt)
#pragma unroll
    for (int nt = 0; nt < 4; ++nt) acc[mt][nt] = (f32x4){0.f, 0.f, 0.f, 0.f};

  auto stage = [&](int buf, int k0) {
#pragma unroll
    for (int i = 0; i < R / 32; ++i) {
      int ar = wave * (R / 4) + i * 8;
      ASYNC16(A + (rowA + ar + klr) * K + k0 + kcs * 8, &As[buf][ar * 64 + lane * 8]);
    }
#pragma unroll
    for (int i = 0; i < 4; ++i) {
      int br = wave * 32 + i * 8;
      ASYNC16(Bt + (rowB + br + klr) * K + k0 + kcs * 8, &Bs[buf][br * 64 + lane * 8]);
    }
  };

  stage(0, 0);
  int iters = K >> 6;
  for (int t = 0; t < iters; ++t) {
    int cur = t & 1;
    __syncthreads();  // drains DMA into buf[cur]; all waves done reading buf[cur^1]
    if (t + 1 < iters) stage(cur ^ 1, (t + 1) * 64);
#pragma unroll
    for (int ks = 0; ks < 2; ++ks) {
      bf16x8 af[MT], bfr[4];
#pragma unroll
      for (int mt = 0; mt < MT; ++mt) {
        int row = wm * (MT * 16) + mt * 16 + qr;
        af[mt] = *(const bf16x8*)&As[cur][row * 64 + (((ks * 4 + quad) ^ (qr & 7)) << 3)];
      }
#pragma unroll
      for (int nt = 0; nt < 4; ++nt) {
        int row = wn * 64 + nt * 16 + qr;
        bfr[nt] = *(const bf16x8*)&Bs[cur][row * 64 + (((ks * 4 + quad) ^ (qr & 7)) << 3)];
      }
#pragma unroll
      for (int mt = 0; mt < MT; ++mt)
#pragma unroll
        for (int nt = 0; nt < 4; ++nt)
          acc[mt][nt] = MFMA16(af[mt], bfr[nt], acc[mt][nt]);
    }
    __syncthreads();  // reads of buf[cur] done before next iter's stage overwrites
  }

  __syncthreads();  // compute done; smem reusable for epilogue staging

  if (mode == 1) {
    // fp32 tile [R][128], padded stride 132 floats (528B, 16B-aligned rows)
    float* epf = (float*)smem;
#pragma unroll
    for (int nt = 0; nt < 4; ++nt) {
      int cl = wn * 64 + nt * 16 + qr;
      float bv = bias[rowB + cl];
#pragma unroll
      for (int mt = 0; mt < MT; ++mt) {
        int rl = wm * (MT * 16) + mt * 16 + quad * 4;
#pragma unroll
        for (int r = 0; r < 4; ++r)
          epf[(rl + r) * 132 + cl] = acc[mt][nt][r] + bv;
      }
    }
    __syncthreads();
    int rr = wave * 2 + (lane >> 5);
    int cc = (lane & 31) * 4;
#pragma unroll
    for (int p = 0; p < R / 8; ++p) {
      int row = p * 8 + rr;
      float4 v = *(const float4*)&epf[row * 132 + cc];
      *(float4*)&outf[(rowA + row) * 1024 + rowB + cc] = v;
    }
  } else if ((int)rowB < 2048) {
    // Q (scaled) / K -> packed QK buffer (stride 2048), coalesced 16B stores
    float sc = ((int)rowB < 1024) ? QSCALE : 1.0f;  // whole 128-col tile is Q or K
    u16* ep = smem;  // [R][128] u16, padded stride 136 (272B, 16B-aligned rows)
#pragma unroll
    for (int nt = 0; nt < 4; ++nt) {
      int cl = wn * 64 + nt * 16 + qr;
      float bv = bias[rowB + cl];
#pragma unroll
      for (int mt = 0; mt < MT; ++mt) {
        int rl = wm * (MT * 16) + mt * 16 + quad * 4;
#pragma unroll
        for (int r = 0; r < 4; ++r)
          ep[(rl + r) * 136 + cl] = f2bf((acc[mt][nt][r] + bv) * sc);
      }
    }
    __syncthreads();
    int rr = wave * 4 + (lane >> 4);
    int cc = (lane & 15) * 8;
#pragma unroll
    for (int p = 0; p < R / 16; ++p) {
      int row = p * 16 + rr;
      u16x8v v = *(const u16x8v*)&ep[row * 136 + cc];
      *(u16x8v*)&qk[(rowA + row) * 2048 + rowB + cc] = v;
    }
  } else {
    // V -> vt[bh][d][n]: stage transposed tile [d][n] in LDS, then write
    // coalesced 256B rows along n.
    u16* ep = smem;  // [128 d][R n] u16, padded stride 136
#pragma unroll
    for (int nt = 0; nt < 4; ++nt) {
      int cl = wn * 64 + nt * 16 + qr;  // d_local 0..127
      float bv = bias[rowB + cl];
#pragma unroll
      for (int mt = 0; mt < MT; ++mt) {
        int rl = wm * (MT * 16) + mt * 16 + quad * 4;  // n_local, multiple of 4
        ushort4 pv;
        pv.x = f2bf(acc[mt][nt][0] + bv);
        pv.y = f2bf(acc[mt][nt][1] + bv);
        pv.z = f2bf(acc[mt][nt][2] + bv);
        pv.w = f2bf(acc[mt][nt][3] + bv);
        *(ushort4*)&ep[cl * 136 + rl] = pv;
      }
    }
    __syncthreads();
    int batch = (int)(rowA >> 11);
    int n_base = (int)(rowA & 2047);
    int rr = wave * 4 + (lane >> 4);
    int cc = (lane & 15) * 8;
#pragma unroll
    for (int p = 0; p < 8; ++p) {
      int d = p * 16 + rr;                      // 0..127 (2 heads x 64)
      int cglob = (int)rowB - 2048 + d;
      int bh_ = batch * 16 + (cglob >> 6);
      u16x8v v = *(const u16x8v*)&ep[d * 136 + cc];
      *(u16x8v*)&vtout[(size_t)bh_ * 131072 + (size_t)(cglob & 63) * 2048 + n_base + cc] = v;
    }
  }
}

// ------------- flash attention v9: round-2 structure + sp software pipeline ----
// Round-5 lesson: the LDS staging IS the prefetch pipeline (grid=512 caps
// residency at 2 blocks/CU regardless of LDS; removing staging exposed raw L2
// latency -> 125us). Keep K/V staging + double-buffer + 1 barrier per 128 keys.
// NEW: the two 64-key half-tiles are software-pipelined to break the serial
// QK->exp->pack->LDS->PV chain: QK1's MFMAs issue with exp1 DEFERRED (z1 kept
// in VGPRs), PV0's 20 MFMAs run before exp1's VALU work, so the MFMA pipe sees
// [QK0][QK1][PV0][PV1] with only exp0 exposed. pw reuse is safe: pf0 is read
// to registers before P1 is written.
__global__ void __launch_bounds__(256) attn_kernel(const u16* __restrict__ qkbuf,
                                                   const u16* __restrict__ vt,
                                                   u16* __restrict__ out) {
  __shared__ alignas(16) u16 kbuf[2][128 * 64];
  __shared__ alignas(16) u16 vbuf[2][64 * 128];
  __shared__ alignas(16) u16 pbuf[4][32 * 64];
  int bh = blockIdx.x;
  int b = bh >> 4, h = bh & 15;
  int m0 = blockIdx.y * 128;
  int tid = threadIdx.x;
  int lane = tid & 63, wave = tid >> 6;
  int qr = lane & 15, quad = lane >> 4;

  const u16* kbase = qkbuf + (size_t)(b * SEQ) * 2048 + 1024 + h * 64;  // K rows, stride 2048
  const u16* vtbase = vt + (size_t)bh * 64 * SEQ;                       // Vt rows, stride 2048
  u16* pw = &pbuf[wave][0];

  int klr = lane >> 3;
  int kcs = (lane & 7) ^ klr;

  // ---- Q fragments (32 rows per wave) ----
  const u16* qbase = qkbuf + (size_t)(b * SEQ + m0 + wave * 32) * 2048 + h * 64;
  bf16x8 qf[2][2];
#pragma unroll
  for (int mt = 0; mt < 2; ++mt)
#pragma unroll
    for (int ks = 0; ks < 2; ++ks)
      qf[mt][ks] = *(const bf16x8*)&qbase[(size_t)(mt * 16 + qr) * 2048 + ks * 32 + quad * 8];

  const bf16x8 vone = __builtin_bit_cast(bf16x8, (u16x8v)((u16)0x3F80));

  f32x4 o[2][4], l5[2];
#pragma unroll
  for (int mt = 0; mt < 2; ++mt) {
    l5[mt] = (f32x4){0.f, 0.f, 0.f, 0.f};
#pragma unroll
    for (int dt = 0; dt < 4; ++dt) o[mt][dt] = (f32x4){0.f, 0.f, 0.f, 0.f};
  }

  auto stage = [&](int buf, int n0) {
#pragma unroll
    for (int i = 0; i < 4; ++i) {
      int kr = wave * 32 + i * 8 + klr;
      ASYNC16(kbase + (size_t)(n0 + kr) * 2048 + kcs * 8,
              &kbuf[buf][(wave * 32 + i * 8) * 64 + lane * 8]);
    }
#pragma unroll
    for (int i = 0; i < 4; ++i) {
      int vr = wave * 16 + i * 4 + (lane >> 4);
      int vcs = ((lane & 7) ^ (vr & 7)) | (lane & 8);
      ASYNC16(vtbase + (size_t)vr * 2048 + n0 + vcs * 8,
              &vbuf[buf][(wave * 16 + i * 4) * 128 + lane * 8]);
    }
  };

  stage(0, 0);

  for (int t = 0; t < 16; ++t) {
    int cur = t & 1;
    __syncthreads();  // own DMA into buf[cur] drained; buf[cur^1] reads finished

    if (t + 1 < 16) stage(cur ^ 1, (t + 1) * 128);

    const u16* kb0 = &kbuf[cur][0];
    const u16* kb1 = &kbuf[cur][64 * 64];
    const u16* vb = &vbuf[cur][0];

    // ======== sp0: QK + exp + pack -> P0 ========
    {
      bf16x8 kf[4][2];
#pragma unroll
      for (int nt = 0; nt < 4; ++nt)
#pragma unroll
        for (int ks = 0; ks < 2; ++ks)
          kf[nt][ks] =
              *(const bf16x8*)&kb0[(nt * 16 + qr) * 64 + (((ks * 4 + quad) ^ (qr & 7)) << 3)];

#pragma unroll
      for (int mt = 0; mt < 2; ++mt)
#pragma unroll
        for (int nt = 0; nt < 4; ++nt) {
          f32x4 z = (f32x4){0.f, 0.f, 0.f, 0.f};
          z = MFMA16(kf[nt][0], qf[mt][0], z);
          z = MFMA16(kf[nt][1], qf[mt][1], z);
          float p0 = __builtin_amdgcn_exp2f(z[0]);
          float p1 = __builtin_amdgcn_exp2f(z[1]);
          float p2 = __builtin_amdgcn_exp2f(z[2]);
          float p3 = __builtin_amdgcn_exp2f(z[3]);
          uint2 pk;
          pk.x = cvt2(p0, p1);
          pk.y = cvt2(p2, p3);
          int nb = nt * 16 + quad * 4;
          int addr = (mt * 16 + qr) * 64 + ((((nb >> 3) ^ (qr & 7)) << 3) | (nb & 7));
          *(uint2*)&pw[addr] = pk;
        }
    }

    // ---- read pf0 (MUST complete before P1 is written) + vf0 ----
    bf16x8 pf0[2][2];
#pragma unroll
    for (int mt = 0; mt < 2; ++mt)
#pragma unroll
      for (int ks = 0; ks < 2; ++ks)
        pf0[mt][ks] =
            *(const bf16x8*)&pw[(mt * 16 + qr) * 64 + (((ks * 4 + quad) ^ (qr & 7)) << 3)];

    bf16x8 vf0[4][2];
#pragma unroll
    for (int dt = 0; dt < 4; ++dt)
#pragma unroll
      for (int ks = 0; ks < 2; ++ks)
        vf0[dt][ks] = *(const bf16x8*)&vb[(dt * 16 + qr) * 128 +
                                          ((((ks * 4 + quad) ^ (qr & 7))) << 3)];

    // ======== sp1 QK: MFMAs issued now, exp DEFERRED (z1 in VGPRs) ========
    f32x4 z1[2][4];
    {
      bf16x8 kg[4][2];
#pragma unroll
      for (int nt = 0; nt < 4; ++nt)
#pragma unroll
        for (int ks = 0; ks < 2; ++ks)
          kg[nt][ks] =
              *(const bf16x8*)&kb1[(nt * 16 + qr) * 64 + (((ks * 4 + quad) ^ (qr & 7)) << 3)];

#pragma unroll
      for (int mt = 0; mt < 2; ++mt)
#pragma unroll
        for (int nt = 0; nt < 4; ++nt) {
          f32x4 z = (f32x4){0.f, 0.f, 0.f, 0.f};
          z = MFMA16(kg[nt][0], qf[mt][0], z);
          z1[mt][nt] = MFMA16(kg[nt][1], qf[mt][1], z);
        }
    }

    // ======== PV0: independent of z1 -> fills the MFMA pipe while exp1 waits ====
#pragma unroll
    for (int mt = 0; mt < 2; ++mt) {
#pragma unroll
      for (int dt = 0; dt < 4; ++dt) {
        o[mt][dt] = MFMA16(pf0[mt][0], vf0[dt][0], o[mt][dt]);
        o[mt][dt] = MFMA16(pf0[mt][1], vf0[dt][1], o[mt][dt]);
      }
      l5[mt] = MFMA16(pf0[mt][0], vone, l5[mt]);
      l5[mt] = MFMA16(pf0[mt][1], vone, l5[mt]);
    }

    // ======== exp1 + pack -> P1 (VALU; overlaps PV0 drain) ========
#pragma unroll
    for (int mt = 0; mt < 2; ++mt)
#pragma unroll
      for (int nt = 0; nt < 4; ++nt) {
        f32x4 z = z1[mt][nt];
        float p0 = __builtin_amdgcn_exp2f(z[0]);
        float p1 = __builtin_amdgcn_exp2f(z[1]);
        float p2 = __builtin_amdgcn_exp2f(z[2]);
        float p3 = __builtin_amdgcn_exp2f(z[3]);
        uint2 pk;
        pk.x = cvt2(p0, p1);
        pk.y = cvt2(p2, p3);
        int nb = nt * 16 + quad * 4;
        int addr = (mt * 16 + qr) * 64 + ((((nb >> 3) ^ (qr & 7)) << 3) | (nb & 7));
        *(uint2*)&pw[addr] = pk;
      }

    // ---- read pf1 + vf1, then PV1 ----
    bf16x8 pf1[2][2];
#pragma unroll
    for (int mt = 0; mt < 2; ++mt)
#pragma unroll
      for (int ks = 0; ks < 2; ++ks)
        pf1[mt][ks] =
            *(const bf16x8*)&pw[(mt * 16 + qr) * 64 + (((ks * 4 + quad) ^ (qr & 7)) << 3)];

    bf16x8 vf1[4][2];
#pragma unroll
    for (int dt = 0; dt < 4; ++dt)
#pragma unroll
      for (int ks = 0; ks < 2; ++ks)
        vf1[dt][ks] = *(const bf16x8*)&vb[(dt * 16 + qr) * 128 +
                                          ((8 + (((ks * 4 + quad) ^ (qr & 7)))) << 3)];

#pragma unroll
    for (int mt = 0; mt < 2; ++mt) {
#pragma unroll
      for (int dt = 0; dt < 4; ++dt) {
        o[mt][dt] = MFMA16(pf1[mt][0], vf1[dt][0], o[mt][dt]);
        o[mt][dt] = MFMA16(pf1[mt][1], vf1[dt][1], o[mt][dt]);
      }
      l5[mt] = MFMA16(pf1[mt][0], vone, l5[mt]);
      l5[mt] = MFMA16(pf1[mt][1], vone, l5[mt]);
    }
  }

  u16* obase = out + (size_t)(b * SEQ + m0 + wave * 32) * CH + h * 64;
#pragma unroll
  for (int mt = 0; mt < 2; ++mt)
#pragma unroll
    for (int r = 0; r < 4; ++r) {
      float inv = 1.0f / l5[mt][r];
#pragma unroll
      for (int dt = 0; dt < 4; ++dt)
        obase[(size_t)(mt * 16 + quad * 4 + r) * CH + dt * 16 + qr] = f2bf(o[mt][dt][r] * inv);
    }
}

extern "C" void kernel_launch(void* const* d_in, const int* in_sizes, int n_in,
                              void* d_out, int out_size, void* d_ws, size_t ws_size,
                              hipStream_t stream) {
  const float* x      = (const float*)d_in[0];
  const float* qkv_w  = (const float*)d_in[1];
  const float* qkv_b  = (const float*)d_in[2];
  const float* proj_w = (const float*)d_in[3];
  const float* proj_b = (const float*)d_in[4];
  float* out = (float*)d_out;

  char* w = (char*)d_ws;
  // ws layout (42 MB):
  //   qkqk  : 4096x2048 bf16 (Q scaled | K, stride 2048) = 16777216 B
  //   xb    : 4096x1024 bf16 = 8388608 B (reused as attn_bf after gemm1)
  //   wprojt: 1024x1024 bf16 = 2097152 B
  //   wqkvt : 3072x1024 bf16 = 6291456 B
  //   vt    : (B*H)x64x2048 bf16 = 8388608 B (written directly by gemm1 epilogue)
  u16* qkqk   = (u16*)w;
  u16* xb     = (u16*)(w + 16777216);
  u16* wprojt = (u16*)(w + 25165824);
  u16* wqkvt  = (u16*)(w + 27262976);
  u16* vt     = (u16*)(w + 33554432);
  u16* attn_bf = xb;

  prep_kernel<<<5120, 256, 0, stream>>>(x, qkv_w, proj_w, xb, wqkvt, wprojt);
  // qkv = x @ qkv_w + b; Q scaled; QK -> qkqk (stride 2048), V -> vt (transposed)
  gemm_kernel<4><<<dim3(24, 32), 256, 0, stream>>>(xb, wqkvt, qkv_b, qkqk, vt, nullptr, 1024, 0);
  attn_kernel<<<dim3(32, 16), 256, 0, stream>>>(qkqk, vt, attn_bf);
  // out = attn @ proj_w + b (fp32)
  gemm_kernel<2><<<dim3(8, 64), 256, 0, stream>>>(attn_bf, wprojt, proj_b, nullptr, nullptr, out, 1024, 1);
}

// Round 7
// 182.216 us; speedup vs baseline: 1.3537x; 1.0995x over previous
//
#include <hip/hip_runtime.h>
#include <cstdint>
#include <cstddef>

typedef __bf16 bf16x8 __attribute__((ext_vector_type(8)));
typedef __bf16 bf16x2v __attribute__((ext_vector_type(2)));
typedef unsigned short u16;
typedef u16 u16x8v __attribute__((ext_vector_type(8)));
typedef float  f32x4  __attribute__((ext_vector_type(4)));
typedef unsigned int u32;

#define MFMA16(a, b, c) __builtin_amdgcn_mfma_f32_16x16x32_bf16((a), (b), (c), 0, 0, 0)
#define ASYNC16(g, l)                                                              \
  __builtin_amdgcn_global_load_lds(                                                \
      (const __attribute__((address_space(1))) unsigned int*)(g),                  \
      (__attribute__((address_space(3))) unsigned int*)(l), 16, 0, 0)

__device__ __forceinline__ u16 f2bf(float f) {
  unsigned u = __builtin_bit_cast(unsigned, f);
  u += 0x7fffu + ((u >> 16) & 1u);
  return (u16)(u >> 16);
}

// packed fp32x2 -> bf16x2 (RNE) via hardware cvt
__device__ __forceinline__ u32 cvt2(float a, float b) {
  bf16x2v t;
  t[0] = (__bf16)a;
  t[1] = (__bf16)b;
  return __builtin_bit_cast(u32, t);
}

#define SEQ 2048
#define CH  1024
#define NH  16
#define HD  64
// log2(e) / sqrt(64) folded into stored Q so softmax uses exp2
#define QSCALE 0.18033688011112042f

// ------------- fused prep: cast x + transpose-cast qkv_w + proj_w -------------
// v2: LDS tile stored pre-transposed so the GLOBAL store side is contiguous ->
// u16x8 (16B) stores instead of 2B/lane scalar stores (8x fewer store instrs).
__global__ void __launch_bounds__(256) prep_kernel(const float* __restrict__ x,
                                                   const float* __restrict__ qkv_w,
                                                   const float* __restrict__ proj_w,
                                                   u16* __restrict__ xb,
                                                   u16* __restrict__ wqkvt,
                                                   u16* __restrict__ wprojt) {
  __shared__ alignas(16) u16 t[64][68];
  int bx = blockIdx.x;
  int tx = threadIdx.x;
  if (bx < 4096) {
    int i = bx * 256 + tx;
    float4 v = ((const float4*)x)[i];
    ushort4 o;
    o.x = f2bf(v.x); o.y = f2bf(v.y); o.z = f2bf(v.z); o.w = f2bf(v.w);
    ((ushort4*)xb)[i] = o;
    return;
  }
  const float* in; u16* out; int R, C, c0, r0;
  if (bx < 4096 + 768) {
    int i = bx - 4096;
    in = qkv_w; out = wqkvt; R = 1024; C = 3072;
    c0 = (i % 48) * 64; r0 = (i / 48) * 64;
  } else {
    int i = bx - 4864;
    in = proj_w; out = wprojt; R = 1024; C = 1024;
    c0 = (i % 16) * 64; r0 = (i / 16) * 64;
  }
  int rr = tx >> 6, cc = tx & 63;
  // t[cc][r] = E(r, cc): store transposed so out rows are contiguous LDS rows
#pragma unroll
  for (int i = 0; i < 16; ++i) {
    int r = i * 4 + rr;
    t[cc][r] = f2bf(in[(size_t)(r0 + r) * C + c0 + cc]);
  }
  __syncthreads();
  // out(row = c0+u, cols r0+w0..w0+7) = t[u][w0..w0+7]  (contiguous)
  int u = tx >> 3;
  int w0 = (tx & 7) * 8;
#pragma unroll
  for (int p = 0; p < 2; ++p) {
    int uu = u + p * 32;
    u16x8v v = *(const u16x8v*)&t[uu][w0];
    *(u16x8v*)&out[(size_t)(c0 + uu) * R + r0 + w0] = v;
  }
}

// ------------- GEMM v4 (round-2 version, measured-best): BK=64, XOR-swizzled LDS,
//               double-buffered staging, two barriers/iter, coalesced epilogue ----
// NOTE round-3/4 lessons: (a) XCD-chunked swizzle REGRESSES (+7us) -- natural
// round-robin already locks 3 fixed B-panel cols per XCD, L2-resident;
// (b) single-barrier variant was ~+3us vs this two-barrier form (lockstep loss).
template <int MT>
__global__ void __launch_bounds__(256) gemm_kernel(const u16* __restrict__ A,
                                                   const u16* __restrict__ Bt,
                                                   const float* __restrict__ bias,
                                                   u16* __restrict__ qk,
                                                   u16* __restrict__ vtout,
                                                   float* __restrict__ outf,
                                                   int K, int mode) {
  constexpr int R = MT * 32;
  __shared__ alignas(16) u16 smem[2 * R * 64 + 2 * 128 * 64];
  auto As = (u16(*)[R * 64])smem;
  auto Bs = (u16(*)[128 * 64])(smem + 2 * R * 64);
  int tid = threadIdx.x;
  int lane = tid & 63, wave = tid >> 6;
  int wm = wave >> 1, wn = wave & 1;
  int qr = lane & 15, quad = lane >> 4;
  size_t rowA = (size_t)blockIdx.y * R;
  size_t rowB = (size_t)blockIdx.x * 128;

  int klr = lane >> 3;
  int kcs = (lane & 7) ^ klr;

  f32x4 acc[MT][4];
#pragma unroll
  for (int mt = 0; mt < MT; ++mt)
#pragma unroll
    for (int nt = 0; nt < 4; ++nt) acc[mt][nt] = (f32x4){0.f, 0.f, 0.f, 0.f};

  auto stage = [&](int buf, int k0) {
#pragma unroll
    for (int i = 0; i < R / 32; ++i) {
      int ar = wave * (R / 4) + i * 8;
      ASYNC16(A + (rowA + ar + klr) * K + k0 + kcs * 8, &As[buf][ar * 64 + lane * 8]);
    }
#pragma unroll
    for (int i = 0; i < 4; ++i) {
      int br = wave * 32 + i * 8;
      ASYNC16(Bt + (rowB + br + klr) * K + k0 + kcs * 8, &Bs[buf][br * 64 + lane * 8]);
    }
  };

  stage(0, 0);
  int iters = K >> 6;
  for (int t = 0; t < iters; ++t) {
    int cur = t & 1;
    __syncthreads();  // drains DMA into buf[cur]; all waves done reading buf[cur^1]
    if (t + 1 < iters) stage(cur ^ 1, (t + 1) * 64);
#pragma unroll
    for (int ks = 0; ks < 2; ++ks) {
      bf16x8 af[MT], bfr[4];
#pragma unroll
      for (int mt = 0; mt < MT; ++mt) {
        int row = wm * (MT * 16) + mt * 16 + qr;
        af[mt] = *(const bf16x8*)&As[cur][row * 64 + (((ks * 4 + quad) ^ (qr & 7)) << 3)];
      }
#pragma unroll
      for (int nt = 0; nt < 4; ++nt) {
        int row = wn * 64 + nt * 16 + qr;
        bfr[nt] = *(const bf16x8*)&Bs[cur][row * 64 + (((ks * 4 + quad) ^ (qr & 7)) << 3)];
      }
#pragma unroll
      for (int mt = 0; mt < MT; ++mt)
#pragma unroll
        for (int nt = 0; nt < 4; ++nt)
          acc[mt][nt] = MFMA16(af[mt], bfr[nt], acc[mt][nt]);
    }
    __syncthreads();  // reads of buf[cur] done before next iter's stage overwrites
  }

  __syncthreads();  // compute done; smem reusable for epilogue staging

  if (mode == 1) {
    // fp32 tile [R][128], padded stride 132 floats (528B, 16B-aligned rows)
    float* epf = (float*)smem;
#pragma unroll
    for (int nt = 0; nt < 4; ++nt) {
      int cl = wn * 64 + nt * 16 + qr;
      float bv = bias[rowB + cl];
#pragma unroll
      for (int mt = 0; mt < MT; ++mt) {
        int rl = wm * (MT * 16) + mt * 16 + quad * 4;
#pragma unroll
        for (int r = 0; r < 4; ++r)
          epf[(rl + r) * 132 + cl] = acc[mt][nt][r] + bv;
      }
    }
    __syncthreads();
    int rr = wave * 2 + (lane >> 5);
    int cc = (lane & 31) * 4;
#pragma unroll
    for (int p = 0; p < R / 8; ++p) {
      int row = p * 8 + rr;
      float4 v = *(const float4*)&epf[row * 132 + cc];
      *(float4*)&outf[(rowA + row) * 1024 + rowB + cc] = v;
    }
  } else if ((int)rowB < 2048) {
    // Q (scaled) / K -> packed QK buffer (stride 2048), coalesced 16B stores
    float sc = ((int)rowB < 1024) ? QSCALE : 1.0f;  // whole 128-col tile is Q or K
    u16* ep = smem;  // [R][128] u16, padded stride 136 (272B, 16B-aligned rows)
#pragma unroll
    for (int nt = 0; nt < 4; ++nt) {
      int cl = wn * 64 + nt * 16 + qr;
      float bv = bias[rowB + cl];
#pragma unroll
      for (int mt = 0; mt < MT; ++mt) {
        int rl = wm * (MT * 16) + mt * 16 + quad * 4;
#pragma unroll
        for (int r = 0; r < 4; ++r)
          ep[(rl + r) * 136 + cl] = f2bf((acc[mt][nt][r] + bv) * sc);
      }
    }
    __syncthreads();
    int rr = wave * 4 + (lane >> 4);
    int cc = (lane & 15) * 8;
#pragma unroll
    for (int p = 0; p < R / 16; ++p) {
      int row = p * 16 + rr;
      u16x8v v = *(const u16x8v*)&ep[row * 136 + cc];
      *(u16x8v*)&qk[(rowA + row) * 2048 + rowB + cc] = v;
    }
  } else {
    // V -> vt[bh][d][n]: stage transposed tile [d][n] in LDS, then write
    // coalesced 256B rows along n.
    u16* ep = smem;  // [128 d][R n] u16, padded stride 136
#pragma unroll
    for (int nt = 0; nt < 4; ++nt) {
      int cl = wn * 64 + nt * 16 + qr;  // d_local 0..127
      float bv = bias[rowB + cl];
#pragma unroll
      for (int mt = 0; mt < MT; ++mt) {
        int rl = wm * (MT * 16) + mt * 16 + quad * 4;  // n_local, multiple of 4
        ushort4 pv;
        pv.x = f2bf(acc[mt][nt][0] + bv);
        pv.y = f2bf(acc[mt][nt][1] + bv);
        pv.z = f2bf(acc[mt][nt][2] + bv);
        pv.w = f2bf(acc[mt][nt][3] + bv);
        *(ushort4*)&ep[cl * 136 + rl] = pv;
      }
    }
    __syncthreads();
    int batch = (int)(rowA >> 11);
    int n_base = (int)(rowA & 2047);
    int rr = wave * 4 + (lane >> 4);
    int cc = (lane & 15) * 8;
#pragma unroll
    for (int p = 0; p < 8; ++p) {
      int d = p * 16 + rr;                      // 0..127 (2 heads x 64)
      int cglob = (int)rowB - 2048 + d;
      int bh_ = batch * 16 + (cglob >> 6);
      u16x8v v = *(const u16x8v*)&ep[d * 136 + cc];
      *(u16x8v*)&vtout[(size_t)bh_ * 131072 + (size_t)(cglob & 63) * 2048 + n_base + cc] = v;
    }
  }
}

// ------------- flash attention v6.3: round-2 main loop (measured-best) +
//               coalesced output epilogue via pw restage -------------
// Main loop bit-identical to round-2 (56.5us): K-tile (128x64) + Vt-tile
// (64x128) DMA'd to LDS, double-buffered, two barriers per 128 keys.
// Rejected by measurement: smaller tiles/higher occupancy (r1), zero-barrier
// streaming (r5), manual sp-pipeline (r6, VGPR 96->148 killed it), setprio (r4).
// NEW (validated pattern from gemm epilogue, -13us): output was 32 scalar 2B
// stores per lane; now staged through the idle wave-private pw slot (4KB) and
// written as 4x u16x8 (16B) stores per lane. No barrier needed (wave-private).
__global__ void __launch_bounds__(256) attn_kernel(const u16* __restrict__ qkbuf,
                                                   const u16* __restrict__ vt,
                                                   u16* __restrict__ out) {
  __shared__ alignas(16) u16 kbuf[2][128 * 64];
  __shared__ alignas(16) u16 vbuf[2][64 * 128];
  __shared__ alignas(16) u16 pbuf[4][32 * 64];
  int bh = blockIdx.x;
  int b = bh >> 4, h = bh & 15;
  int m0 = blockIdx.y * 128;
  int tid = threadIdx.x;
  int lane = tid & 63, wave = tid >> 6;
  int qr = lane & 15, quad = lane >> 4;

  const u16* kbase = qkbuf + (size_t)(b * SEQ) * 2048 + 1024 + h * 64;  // K rows, stride 2048
  const u16* vtbase = vt + (size_t)bh * 64 * SEQ;                       // Vt rows, stride 2048
  u16* pw = &pbuf[wave][0];

  int klr = lane >> 3;
  int kcs = (lane & 7) ^ klr;

  // ---- Q fragments (32 rows per wave) ----
  const u16* qbase = qkbuf + (size_t)(b * SEQ + m0 + wave * 32) * 2048 + h * 64;
  bf16x8 qf[2][2];
#pragma unroll
  for (int mt = 0; mt < 2; ++mt)
#pragma unroll
    for (int ks = 0; ks < 2; ++ks)
      qf[mt][ks] = *(const bf16x8*)&qbase[(size_t)(mt * 16 + qr) * 2048 + ks * 32 + quad * 8];

  const bf16x8 vone = __builtin_bit_cast(bf16x8, (u16x8v)((u16)0x3F80));

  f32x4 o[2][4], l5[2];
#pragma unroll
  for (int mt = 0; mt < 2; ++mt) {
    l5[mt] = (f32x4){0.f, 0.f, 0.f, 0.f};
#pragma unroll
    for (int dt = 0; dt < 4; ++dt) o[mt][dt] = (f32x4){0.f, 0.f, 0.f, 0.f};
  }

  auto stage = [&](int buf, int n0) {
#pragma unroll
    for (int i = 0; i < 4; ++i) {
      int kr = wave * 32 + i * 8 + klr;
      ASYNC16(kbase + (size_t)(n0 + kr) * 2048 + kcs * 8,
              &kbuf[buf][(wave * 32 + i * 8) * 64 + lane * 8]);
    }
#pragma unroll
    for (int i = 0; i < 4; ++i) {
      int vr = wave * 16 + i * 4 + (lane >> 4);
      int vcs = ((lane & 7) ^ (vr & 7)) | (lane & 8);
      ASYNC16(vtbase + (size_t)vr * 2048 + n0 + vcs * 8,
              &vbuf[buf][(wave * 16 + i * 4) * 128 + lane * 8]);
    }
  };

  stage(0, 0);

  for (int t = 0; t < 16; ++t) {
    int cur = t & 1;
    __syncthreads();

    if (t + 1 < 16) stage(cur ^ 1, (t + 1) * 128);

#pragma unroll
    for (int sp = 0; sp < 2; ++sp) {
      const u16* kb = &kbuf[cur][sp * 64 * 64];
      const u16* vb = &vbuf[cur][0];

      bf16x8 kf[4][2];
#pragma unroll
      for (int nt = 0; nt < 4; ++nt)
#pragma unroll
        for (int ks = 0; ks < 2; ++ks)
          kf[nt][ks] =
              *(const bf16x8*)&kb[(nt * 16 + qr) * 64 + (((ks * 4 + quad) ^ (qr & 7)) << 3)];

#pragma unroll
      for (int mt = 0; mt < 2; ++mt)
#pragma unroll
        for (int nt = 0; nt < 4; ++nt) {
          f32x4 z = (f32x4){0.f, 0.f, 0.f, 0.f};
          z = MFMA16(kf[nt][0], qf[mt][0], z);
          z = MFMA16(kf[nt][1], qf[mt][1], z);
          float p0 = __builtin_amdgcn_exp2f(z[0]);
          float p1 = __builtin_amdgcn_exp2f(z[1]);
          float p2 = __builtin_amdgcn_exp2f(z[2]);
          float p3 = __builtin_amdgcn_exp2f(z[3]);
          uint2 pk;
          pk.x = cvt2(p0, p1);
          pk.y = cvt2(p2, p3);
          int nb = nt * 16 + quad * 4;
          int addr = (mt * 16 + qr) * 64 + ((((nb >> 3) ^ (qr & 7)) << 3) | (nb & 7));
          *(uint2*)&pw[addr] = pk;
        }

      bf16x8 vf[4][2];
#pragma unroll
      for (int dt = 0; dt < 4; ++dt)
#pragma unroll
        for (int ks = 0; ks < 2; ++ks)
          vf[dt][ks] = *(const bf16x8*)&vb[(dt * 16 + qr) * 128 +
                                           ((sp * 8 + ((ks * 4 + quad) ^ (qr & 7))) << 3)];

      bf16x8 pf[2][2];
#pragma unroll
      for (int mt = 0; mt < 2; ++mt)
#pragma unroll
        for (int ks = 0; ks < 2; ++ks)
          pf[mt][ks] =
              *(const bf16x8*)&pw[(mt * 16 + qr) * 64 + (((ks * 4 + quad) ^ (qr & 7)) << 3)];

#pragma unroll
      for (int mt = 0; mt < 2; ++mt) {
#pragma unroll
        for (int dt = 0; dt < 4; ++dt) {
          o[mt][dt] = MFMA16(pf[mt][0], vf[dt][0], o[mt][dt]);
          o[mt][dt] = MFMA16(pf[mt][1], vf[dt][1], o[mt][dt]);
        }
        l5[mt] = MFMA16(pf[mt][0], vone, l5[mt]);
        l5[mt] = MFMA16(pf[mt][1], vone, l5[mt]);
      }
    }
  }

  // ---- coalesced output epilogue: stage o into wave-private pw, 16B stores ----
#pragma unroll
  for (int mt = 0; mt < 2; ++mt)
#pragma unroll
    for (int r = 0; r < 4; ++r) {
      float inv = 1.0f / l5[mt][r];
      int row = mt * 16 + quad * 4 + r;
#pragma unroll
      for (int dt = 0; dt < 4; ++dt)
        pw[row * 64 + dt * 16 + qr] = f2bf(o[mt][dt][r] * inv);
    }
  // pw is wave-private: no barrier, compiler inserts lgkmcnt before reads
  u16* ob = out + (size_t)(b * SEQ + m0 + wave * 32) * CH + h * 64;
  int rr2 = lane >> 1;
  int d0 = (lane & 1) * 32;
#pragma unroll
  for (int p = 0; p < 4; ++p) {
    u16x8v v = *(const u16x8v*)&pw[rr2 * 64 + d0 + p * 8];
    *(u16x8v*)&ob[(size_t)rr2 * CH + d0 + p * 8] = v;
  }
}

extern "C" void kernel_launch(void* const* d_in, const int* in_sizes, int n_in,
                              void* d_out, int out_size, void* d_ws, size_t ws_size,
                              hipStream_t stream) {
  const float* x      = (const float*)d_in[0];
  const float* qkv_w  = (const float*)d_in[1];
  const float* qkv_b  = (const float*)d_in[2];
  const float* proj_w = (const float*)d_in[3];
  const float* proj_b = (const float*)d_in[4];
  float* out = (float*)d_out;

  char* w = (char*)d_ws;
  // ws layout (42 MB):
  //   qkqk  : 4096x2048 bf16 (Q scaled | K, stride 2048) = 16777216 B
  //   xb    : 4096x1024 bf16 = 8388608 B (reused as attn_bf after gemm1)
  //   wprojt: 1024x1024 bf16 = 2097152 B
  //   wqkvt : 3072x1024 bf16 = 6291456 B
  //   vt    : (B*H)x64x2048 bf16 = 8388608 B (written directly by gemm1 epilogue)
  u16* qkqk   = (u16*)w;
  u16* xb     = (u16*)(w + 16777216);
  u16* wprojt = (u16*)(w + 25165824);
  u16* wqkvt  = (u16*)(w + 27262976);
  u16* vt     = (u16*)(w + 33554432);
  u16* attn_bf = xb;

  prep_kernel<<<5120, 256, 0, stream>>>(x, qkv_w, proj_w, xb, wqkvt, wprojt);
  // qkv = x @ qkv_w + b; Q scaled; QK -> qkqk (stride 2048), V -> vt (transposed)
  gemm_kernel<4><<<dim3(24, 32), 256, 0, stream>>>(xb, wqkvt, qkv_b, qkqk, vt, nullptr, 1024, 0);
  attn_kernel<<<dim3(32, 16), 256, 0, stream>>>(qkqk, vt, attn_bf);
  // out = attn @ proj_w + b (fp32)
  gemm_kernel<2><<<dim3(8, 64), 256, 0, stream>>>(attn_bf, wprojt, proj_b, nullptr, nullptr, out, 1024, 1);
}